// Round 15
// baseline (281.191 us; speedup 1.0000x reference)
//
#include <hip/hip_runtime.h>

// LightGCN forward: two gather-scale-scatter-sum propagations.
// Round 15: single-pass XCD-private cell CSR build. r14 post-mortem: gathers
// are latency-pinned at ~60us (invariant to bytes/occupancy/MLP) -> attack
// the 45us build instead. hist+scan+partition replaced by ONE scatter pass:
// fixed-capacity cells payl[(xcd*NB+bucket)*384] + L2-resident atomic
// cursors (same-XCD appends only -> tail lines live in one L2; r4-proven).
// Overflow (+8 sigma, ~impossible) spills to a global list the gather drains
// predicated. xscale folded at scatter-0; scatter-1 runs after gather0 to
// fold hscale; src stored premultiplied. int8 rows (r14), quad-gather (r6/r9).
//
// Sizes: x [100000,128] f32; E0=1.6M edges -> 50000 dsts; E1=0.8M -> 25000.

#define DIMS 128
#define BK   64      // dsts per bucket
#define BKSH 6
#define CAPC 384     // per-(xcd,bucket) cell capacity (mean 256, +8 sigma)
#define LPC  (8 * CAPC)   // max LDS-staged edges per bucket = 3072

__device__ __forceinline__ unsigned bf16_1(float a) {
  unsigned u = __float_as_uint(a);
  return (u + 0x7fffu + ((u >> 16) & 1u)) >> 16;   // RNE
}

__device__ __forceinline__ int xcc_id() {
  unsigned x;
  asm volatile("s_getreg_b32 %0, hwreg(HW_REG_XCC_ID)" : "=s"(x));
  return (int)(x & 7);
}

// --------------------------------- K1: int8 row quantization of x (16 ln/row)
__global__ __launch_bounds__(256) void cvt_q(
    const float* __restrict__ xf, uint2* __restrict__ xq,
    float* __restrict__ xscale, int NSRC) {
  int gi = blockIdx.x * 256 + threadIdx.x;
  int row = gi >> 4, c = gi & 15;
  if (row >= NSRC) return;
  const float4* xf4 = (const float4*)xf;
  float4 v0 = xf4[(size_t)row * 32 + c * 2];
  float4 v1 = xf4[(size_t)row * 32 + c * 2 + 1];
  float m = fmaxf(fmaxf(fmaxf(fabsf(v0.x), fabsf(v0.y)),
                        fmaxf(fabsf(v0.z), fabsf(v0.w))),
                  fmaxf(fmaxf(fabsf(v1.x), fabsf(v1.y)),
                        fmaxf(fabsf(v1.z), fabsf(v1.w))));
  m = fmaxf(m, __shfl_xor(m, 1));
  m = fmaxf(m, __shfl_xor(m, 2));
  m = fmaxf(m, __shfl_xor(m, 4));
  m = fmaxf(m, __shfl_xor(m, 8));
  float inv = (m > 0.f) ? 127.0f / m : 0.f;
  int q0 = (int)rintf(v0.x * inv), q1 = (int)rintf(v0.y * inv);
  int q2 = (int)rintf(v0.z * inv), q3 = (int)rintf(v0.w * inv);
  int q4 = (int)rintf(v1.x * inv), q5 = (int)rintf(v1.y * inv);
  int q6 = (int)rintf(v1.z * inv), q7 = (int)rintf(v1.w * inv);
  unsigned lo = (q0 & 255) | ((q1 & 255) << 8) |
                ((q2 & 255) << 16) | ((q3 & 255) << 24);
  unsigned hi = (q4 & 255) | ((q5 & 255) << 8) |
                ((q6 & 255) << 16) | ((q7 & 255) << 24);
  xq[(size_t)row * 16 + c] = make_uint2(lo, hi);
  if (c == 0) xscale[row] = m * (1.0f / 127.0f);
}

// ---------------- K2/K4: single-pass cell scatter (XCD-private cells).
// Payload: x = src*16 (premultiplied uint2-row index); y = bf16(ew*scl)<<16
// | dst-low-6. Overflow -> global list (bucket id in ovfb).
__global__ __launch_bounds__(256) void scatter_cell(
    const int* __restrict__ src, const int* __restrict__ dst,
    const float* __restrict__ ew, const float* __restrict__ scl,
    int* __restrict__ cur, int2* __restrict__ payl,
    int* __restrict__ ovfc, int2* __restrict__ ovfp, int* __restrict__ ovfb,
    int E, int NB) {
  int e = blockIdx.x * 256 + threadIdx.x;
  if (e >= E) return;
  int x = xcc_id();
  int d = dst[e];
  int b = d >> BKSH;
  int s = src[e];
  float ws = ew[e] * scl[s];
  int2 pv = make_int2(s << 4,
                      (int)((bf16_1(ws) << 16) | (unsigned)(d & (BK - 1))));
  int cell = x * NB + b;
  int pos = atomicAdd(&cur[cell], 1);
  if (pos < CAPC) {
    payl[(size_t)cell * CAPC + pos] = pv;
  } else {
    int o = atomicAdd(ovfc, 1);
    ovfp[o] = pv;
    ovfb[o] = b;
  }
}

// ------------------------------- K3/K5: cell gather (one workgroup/bucket).
// Stage the bucket's 8 cells into LDS, counting-sort by dst-low, then per-dst
// quad-register-gather (stride 4): lane=(rr=edge slot, c=8-col chunk), uint2
// int8-row loads, shfl_xor combine. OUT_I8 epilogue re-quantizes + scale.
#define EDGE_BLOCK8(ws, u)                                      \
  {                                                             \
    a0 += (float)((int)((u).x << 24) >> 24) * (ws);             \
    a1 += (float)((int)((u).x << 16) >> 24) * (ws);             \
    a2 += (float)((int)((u).x << 8) >> 24) * (ws);              \
    a3 += (float)((int)(u).x >> 24) * (ws);                     \
    a4 += (float)((int)((u).y << 24) >> 24) * (ws);             \
    a5 += (float)((int)((u).y << 16) >> 24) * (ws);             \
    a6 += (float)((int)((u).y << 8) >> 24) * (ws);              \
    a7 += (float)((int)(u).y >> 24) * (ws);                     \
  }

template <bool OUT_I8>
__global__ __launch_bounds__(512) void gather_cell(
    const uint2* __restrict__ feat, const int* __restrict__ cur,
    const int2* __restrict__ payl, const int* __restrict__ ovfc,
    const int2* __restrict__ ovfp, const int* __restrict__ ovfb,
    void* __restrict__ outp, float* __restrict__ oscale, int n_dst, int NB) {
  __shared__ int2 lp[LPC];
  __shared__ int cnt[BK], base[BK], cnt2[BK];
  __shared__ int segc[8];
  const int b = blockIdx.x;
  const int tid = threadIdx.x;
  if (tid < BK) { cnt[tid] = 0; cnt2[tid] = 0; }
  if (tid < 8) segc[tid] = min(cur[tid * NB + b], CAPC);
  __syncthreads();
  for (int x = 0; x < 8; ++x) {           // histogram over the 8 cells
    const int n = segc[x];
    const int2* sp = payl + (size_t)(x * NB + b) * CAPC;
    for (int j = tid; j < n; j += 512)
      atomicAdd(&cnt[sp[j].y & (BK - 1)], 1);
  }
  __syncthreads();
  if (tid < 64) {                         // exclusive scan of cnt[64], wave 0
    int v = cnt[tid];
    int s = v;
    for (int off = 1; off < 64; off <<= 1) {
      int u = __shfl_up(s, off);
      if (tid >= off) s += u;
    }
    base[tid] = s - v;
  }
  __syncthreads();
  for (int x = 0; x < 8; ++x) {           // place
    const int n = segc[x];
    const int2* sp = payl + (size_t)(x * NB + b) * CAPC;
    for (int j = tid; j < n; j += 512) {
      int2 p = sp[j];
      int dl = p.y & (BK - 1);
      lp[base[dl] + atomicAdd(&cnt2[dl], 1)] = p;
    }
  }
  __syncthreads();
  const int novf = *ovfc;                 // normally 0
  const int wave = tid >> 6;              // 0..7
  const int lane = tid & 63;
  const int rr = lane >> 4;
  const int c  = lane & 15;
  for (int dl = wave; dl < BK; dl += 8) {
    const int row = b * BK + dl;
    if (row >= n_dst) break;              // only last bucket; monotone in dl
    const int bg = base[dl];
    const int en = bg + cnt[dl];
    float a0 = 0.f, a1 = 0.f, a2 = 0.f, a3 = 0.f;
    float a4 = 0.f, a5 = 0.f, a6 = 0.f, a7 = 0.f;
    for (int j = bg; j < en; j += 4) {    // 4 edges per wave-instruction
      int jj = j + rr;
      int2 p = (jj < en) ? lp[jj] : make_int2(0, 0);
      float ws = __uint_as_float((unsigned)p.y & 0xffff0000u);
      uint2 u = feat[(size_t)p.x + c];
      EDGE_BLOCK8(ws, u);
    }
    if (novf > 0) {                       // drain overflow list (predicated)
      for (int j = 0; j < novf; j += 4) {
        int jj = j + rr;
        bool in = (jj < novf);
        int2 p = in ? ovfp[jj] : make_int2(0, 0);
        bool mine = in && (ovfb[jj] == b) && ((p.y & (BK - 1)) == dl);
        float ws = mine ? __uint_as_float((unsigned)p.y & 0xffff0000u) : 0.f;
        uint2 u = feat[(size_t)p.x + c];
        EDGE_BLOCK8(ws, u);
      }
    }
    a0 += __shfl_xor(a0, 16); a0 += __shfl_xor(a0, 32);
    a1 += __shfl_xor(a1, 16); a1 += __shfl_xor(a1, 32);
    a2 += __shfl_xor(a2, 16); a2 += __shfl_xor(a2, 32);
    a3 += __shfl_xor(a3, 16); a3 += __shfl_xor(a3, 32);
    a4 += __shfl_xor(a4, 16); a4 += __shfl_xor(a4, 32);
    a5 += __shfl_xor(a5, 16); a5 += __shfl_xor(a5, 32);
    a6 += __shfl_xor(a6, 16); a6 += __shfl_xor(a6, 32);
    a7 += __shfl_xor(a7, 16); a7 += __shfl_xor(a7, 32);
    if (OUT_I8) {
      float m = fmaxf(fmaxf(fmaxf(fabsf(a0), fabsf(a1)),
                            fmaxf(fabsf(a2), fabsf(a3))),
                      fmaxf(fmaxf(fabsf(a4), fabsf(a5)),
                            fmaxf(fabsf(a6), fabsf(a7))));
      m = fmaxf(m, __shfl_xor(m, 1));
      m = fmaxf(m, __shfl_xor(m, 2));
      m = fmaxf(m, __shfl_xor(m, 4));
      m = fmaxf(m, __shfl_xor(m, 8));
      m = fmaxf(m, __shfl_xor(m, 16));
      m = fmaxf(m, __shfl_xor(m, 32));
      float inv = (m > 0.f) ? 127.0f / m : 0.f;
      if (rr == 0) {
        int q0 = (int)rintf(a0 * inv), q1 = (int)rintf(a1 * inv);
        int q2 = (int)rintf(a2 * inv), q3 = (int)rintf(a3 * inv);
        int q4 = (int)rintf(a4 * inv), q5 = (int)rintf(a5 * inv);
        int q6 = (int)rintf(a6 * inv), q7 = (int)rintf(a7 * inv);
        unsigned lo = (q0 & 255) | ((q1 & 255) << 8) |
                      ((q2 & 255) << 16) | ((q3 & 255) << 24);
        unsigned hi = (q4 & 255) | ((q5 & 255) << 8) |
                      ((q6 & 255) << 16) | ((q7 & 255) << 24);
        ((uint2*)outp)[(size_t)row * 16 + c] = make_uint2(lo, hi);
      }
      if (lane == 0) oscale[row] = m * (1.0f / 127.0f);
    } else {
      if (rr < 2) {
        ((float4*)outp)[(size_t)row * 32 + c * 2 + rr] =
            (rr == 0) ? make_float4(a0, a1, a2, a3)
                      : make_float4(a4, a5, a6, a7);
      }
    }
  }
}

// ------------------------------------------------- fallback (round-1 path)
#define COLG 32
__global__ __launch_bounds__(256) void prop_atomic(
    const float* __restrict__ x, const int* __restrict__ src,
    const int* __restrict__ dst, const float* __restrict__ ew,
    float* __restrict__ out, int E) {
  long long idx = (long long)blockIdx.x * blockDim.x + threadIdx.x;
  long long total = (long long)E * COLG;
  if (idx >= total) return;
  int e = (int)(idx >> 5);
  int cg = (int)(idx & 31);
  int s = src[e];
  int d = dst[e];
  float w = ew[e];
  const float4 v = *reinterpret_cast<const float4*>(x + (size_t)s * DIMS + cg * 4);
  float* o = out + (size_t)d * DIMS + cg * 4;
  atomicAdd(o + 0, v.x * w);
  atomicAdd(o + 1, v.y * w);
  atomicAdd(o + 2, v.z * w);
  atomicAdd(o + 3, v.w * w);
}

// --------------------------------------------------------------- launcher

static inline size_t align_up(size_t v, size_t a) { return (v + a - 1) / a * a; }

extern "C" void kernel_launch(void* const* d_in, const int* in_sizes, int n_in,
                              void* d_out, int out_size, void* d_ws, size_t ws_size,
                              hipStream_t stream) {
  const float* x    = (const float*)d_in[0];
  const int*   src0 = (const int*)d_in[1];
  const int*   dst0 = (const int*)d_in[2];
  const float* ew0  = (const float*)d_in[3];
  const int*   src1 = (const int*)d_in[4];
  const int*   dst1 = (const int*)d_in[5];
  const float* ew1  = (const float*)d_in[6];

  const int N_SRC0 = in_sizes[0] / DIMS;  // 100000
  const int E0 = in_sizes[1];             // 1600000
  const int E1 = in_sizes[4];             // 800000
  const int N_DST0 = 50000;
  const int N_DST1 = 25000;

  const int NB0 = (N_DST0 + BK - 1) / BK;   // 782
  const int NB1 = (N_DST1 + BK - 1) / BK;   // 391

  float* out = (float*)d_out;

  // --- workspace layout ---
  char* ws = (char*)d_ws;
  size_t off = 0;
  uint2* xq     = (uint2*)(ws + off); off = align_up(off + (size_t)N_SRC0 * 16 * 8, 16);
  float* xscale = (float*)(ws + off); off = align_up(off + (size_t)N_SRC0 * 4, 16);
  uint2* hq     = (uint2*)(ws + off); off = align_up(off + (size_t)N_DST0 * 16 * 8, 16);
  float* hscale = (float*)(ws + off); off = align_up(off + (size_t)N_DST0 * 4, 16);
  int* cur0     = (int*)(ws + off);   off = align_up(off + (size_t)8 * NB0 * 4, 16);
  int* cur1     = (int*)(ws + off);   off = align_up(off + (size_t)8 * NB1 * 4, 16);
  int* ovfc     = (int*)(ws + off);   off = align_up(off + 2 * 4, 16);
  int2* payl0   = (int2*)(ws + off);  off = align_up(off + (size_t)8 * NB0 * CAPC * 8, 16);
  int2* payl1   = (int2*)(ws + off);  off = align_up(off + (size_t)8 * NB1 * CAPC * 8, 16);
  int2* ovfp0   = (int2*)(ws + off);  off = align_up(off + (size_t)E0 * 8, 16);
  int* ovfb0    = (int*)(ws + off);   off = align_up(off + (size_t)E0 * 4, 16);
  int2* ovfp1   = (int2*)(ws + off);  off = align_up(off + (size_t)E1 * 8, 16);
  int* ovfb1    = (int*)(ws + off);   off = align_up(off + (size_t)E1 * 4, 16);
  const size_t needed = off;

  if (ws_size < needed) {
    float* h = (float*)d_ws;
    hipMemsetAsync(h, 0, (size_t)N_DST0 * DIMS * 4, stream);
    hipMemsetAsync(out, 0, (size_t)N_DST1 * DIMS * 4, stream);
    long long t0 = (long long)E0 * COLG;
    prop_atomic<<<(int)((t0 + 255) / 256), 256, 0, stream>>>(x, src0, dst0, ew0, h, E0);
    long long t1 = (long long)E1 * COLG;
    prop_atomic<<<(int)((t1 + 255) / 256), 256, 0, stream>>>(h, src1, dst1, ew1, out, E1);
    return;
  }

  // 0. zero cursors (cells + overflow)
  hipMemsetAsync(cur0, 0, (size_t)8 * NB0 * 4, stream);
  hipMemsetAsync(cur1, 0, (size_t)8 * NB1 * 4, stream);
  hipMemsetAsync(ovfc, 0, 2 * 4, stream);

  // K1: int8 row quantization of x
  cvt_q<<<(N_SRC0 * 16 + 255) / 256, 256, 0, stream>>>(x, xq, xscale, N_SRC0);

  // K2: stage-0 cell scatter (folds xscale into weight)
  scatter_cell<<<(E0 + 255) / 256, 256, 0, stream>>>(
      src0, dst0, ew0, xscale, cur0, payl0, &ovfc[0], ovfp0, ovfb0, E0, NB0);

  // K3: stage-0 gather: hq[dst0] += int8(xq[src0]) * w  (int8 out + hscale)
  gather_cell<true><<<NB0, 512, 0, stream>>>(
      xq, cur0, payl0, &ovfc[0], ovfp0, ovfb0, (void*)hq, hscale, N_DST0, NB0);

  // K4: stage-1 cell scatter (folds hscale; must follow gather0)
  scatter_cell<<<(E1 + 255) / 256, 256, 0, stream>>>(
      src1, dst1, ew1, hscale, cur1, payl1, &ovfc[1], ovfp1, ovfb1, E1, NB1);

  // K5: stage-1 gather: out[dst1] += int8(hq[src1]) * w  (f32 out)
  gather_cell<false><<<NB1, 512, 0, stream>>>(
      hq, cur1, payl1, &ovfc[1], ovfp1, ovfb1, (void*)out, (float*)nullptr,
      N_DST1, NB1);
}

// Round 16
// 168.451 us; speedup vs baseline: 1.6693x; 1.6693x over previous
//
#include <hip/hip_runtime.h>

// LightGCN forward: two gather-scale-scatter-sum propagations.
// Round 16: dual-destination gather. r15's cell scatter regressed (revert to
// r9 build + r13 chunk swizzle). Gather evidence across r9-r14: ~60us/stage,
// invariant to bytes/occupancy/grid -> Little's-law equilibrium at ONE
// outstanding row-load per wave (32 waves x 128B ~ 4KB/CU in flight @ ~700cy
// = ~3.5 TB/s). Fix: each wave processes a PAIR of dsts (dl, dl+8) with two
// accumulator sets and two independent stride-4 edge streams -> 2 loads in
// flight per wave, ~12% dummy waste (vs r11's 25% single-dst stride-16).
// bf16 features (r5), quad-gather lanes (r6), bucket-CSR (r7), parallel
// scans + atomic base (r8/r10), 512-thread gather (r9), chunk swizzle (r13).
//
// Sizes: x [100000,128] f32; E0=1.6M edges -> 50000 dsts; E1=0.8M -> 25000.

#define DIMS 128
#define BK   64      // dsts per bucket
#define BKSH 6
#define CAP  4096    // LDS-staged edges per bucket (mean 2048, +45 sigma)
#define CH   8192    // edges per partition chunk

__device__ __forceinline__ unsigned bf16_1(float a) {
  unsigned u = __float_as_uint(a);
  return (u + 0x7fffu + ((u >> 16) & 1u)) >> 16;   // RNE
}
__device__ __forceinline__ unsigned pack_bf16(float a, float b) {
  return bf16_1(a) | (bf16_1(b) << 16);
}

// Bijective XCD swizzle (m204): blocks with equal (b&7) [one XCD under
// round-robin dispatch] get a CONTIGUOUS chunk range.
__device__ __forceinline__ int chunk_swz(int b, int NW) {
  const int q = NW >> 3, r = NW & 7, x = b & 7;
  return (x < r ? x * (q + 1) : r * (q + 1) + (x - r) * q) + (b >> 3);
}

// ---------------------------------------- K1: per-chunk bucket histogram + cvt
__global__ __launch_bounds__(256) void hist_cvt(
    const int* __restrict__ dst0, const int* __restrict__ dst1,
    const float* __restrict__ xf, uint4* __restrict__ xbf4,
    int* __restrict__ wgcnt0, int* __restrict__ wgcnt1,
    int E0, int E1, int NB0, int NB1, int NW0, int NW1, long long n8) {
  int b = blockIdx.x;
  if (b < NW0 + NW1) {
    __shared__ int hist[1024];
    const int s1 = (b >= NW0);
    const int w  = s1 ? chunk_swz(b - NW0, NW1) : chunk_swz(b, NW0);
    const int E  = s1 ? E1 : E0;
    const int NB = s1 ? NB1 : NB0;
    const int* dst = s1 ? dst1 : dst0;
    int* wgcnt = s1 ? wgcnt1 : wgcnt0;
    for (int i = threadIdx.x; i < NB; i += 256) hist[i] = 0;
    __syncthreads();
    const int beg = w * CH, end = min(beg + CH, E);
    for (int e = beg + threadIdx.x; e < end; e += 256)
      atomicAdd(&hist[dst[e] >> BKSH], 1);
    __syncthreads();
    for (int i = threadIdx.x; i < NB; i += 256)
      wgcnt[w * NB + i] = hist[i];          // [chunk][bucket] -> coalesced
  } else {
    long long t = (long long)(b - NW0 - NW1) * 256 + threadIdx.x;
    if (t < n8) {
      const float4* xf4 = (const float4*)xf;
      float4 v0 = xf4[t * 2], v1 = xf4[t * 2 + 1];
      xbf4[t] = make_uint4(pack_bf16(v0.x, v0.y), pack_bf16(v0.z, v0.w),
                           pack_bf16(v1.x, v1.y), pack_bf16(v1.z, v1.w));
    }
  }
}

// ---------------- K2: per-bucket chunk-prefix scan + global base via atomic.
__global__ __launch_bounds__(256) void scan_cols(
    int* __restrict__ wgcnt0, int* __restrict__ wgcnt1,
    int* __restrict__ gcur, int2* __restrict__ rg0, int2* __restrict__ rg1,
    int NB0, int NB1, int NW0, int NW1) {
  __shared__ int part[256];
  int b = blockIdx.x;
  const int s1 = (b >= NB0);
  const int i = s1 ? b - NB0 : b;
  int* wgcnt = s1 ? wgcnt1 : wgcnt0;
  int2* rg   = s1 ? rg1 : rg0;
  const int NB = s1 ? NB1 : NB0;
  const int NW = s1 ? NW1 : NW0;
  const int t = threadIdx.x;
  int v = (t < NW) ? wgcnt[t * NB + i] : 0;
  part[t] = v;
  __syncthreads();
  for (int off = 1; off < 256; off <<= 1) {
    int u = (t >= off) ? part[t - off] : 0;
    __syncthreads();
    part[t] += u;
    __syncthreads();
  }
  if (t < NW) wgcnt[t * NB + i] = part[t] - v;   // exclusive (bucket-local)
  if (t == 255) {
    int tot = part[255];
    int base = atomicAdd(&gcur[s1], tot);
    rg[i] = make_int2(base, base + tot);
  }
}

// -------------------------------- K3: chunked partition into bucket regions.
// Payload: x = src; y = (bf16(w) << 16) | (dst & 63). XCD-swizzled chunks.
__global__ __launch_bounds__(512) void partition_k(
    const int* __restrict__ src0, const int* __restrict__ dst0,
    const float* __restrict__ ew0, const int* __restrict__ src1,
    const int* __restrict__ dst1, const float* __restrict__ ew1,
    const int* __restrict__ wgcnt0, const int* __restrict__ wgcnt1,
    const int2* __restrict__ rg0, const int2* __restrict__ rg1,
    int2* __restrict__ payl0, int2* __restrict__ payl1,
    int E0, int E1, int NB0, int NB1, int NW0, int NW1) {
  __shared__ int cur[1024];
  int b = blockIdx.x;
  const int s1 = (b >= NW0);
  const int w  = s1 ? chunk_swz(b - NW0, NW1) : chunk_swz(b, NW0);
  const int E  = s1 ? E1 : E0;
  const int NB = s1 ? NB1 : NB0;
  const int* src = s1 ? src1 : src0;
  const int* dst = s1 ? dst1 : dst0;
  const float* ew = s1 ? ew1 : ew0;
  const int* wgcnt = s1 ? wgcnt1 : wgcnt0;
  const int2* rg = s1 ? rg1 : rg0;
  int2* payl = s1 ? payl1 : payl0;
  for (int i = threadIdx.x; i < NB; i += 512)
    cur[i] = rg[i].x + wgcnt[w * NB + i];
  __syncthreads();
  const int beg = w * CH, end = min(beg + CH, E);
  for (int e = beg + threadIdx.x; e < end; e += 512) {
    int d = dst[e];
    int pos = atomicAdd(&cur[d >> BKSH], 1);
    payl[pos] = make_int2(src[e],
                          (int)((bf16_1(ew[e]) << 16) | (unsigned)(d & (BK - 1))));
  }
}

// ------------------------------- K4/K5: bucket gather (one workgroup/bucket).
// 512 threads = 8 waves. LDS counting-sort by dst-low, then DUAL-DST gather:
// each wave walks the edge lists of dsts (dl, dl+8) in lock-step, stride 4 —
// two independent uint4 row loads in flight per iteration. lane=(rr=edge
// slot 0..3, c=16B chunk 0..15); shfl_xor combine; vector store per dst row.
#define ACC8(a0,a1,a2,a3,a4,a5,a6,a7, wgt, u)                   \
  {                                                             \
    a0 += __uint_as_float((u).x << 16) * (wgt);                 \
    a1 += __uint_as_float((u).x & 0xffff0000u) * (wgt);         \
    a2 += __uint_as_float((u).y << 16) * (wgt);                 \
    a3 += __uint_as_float((u).y & 0xffff0000u) * (wgt);         \
    a4 += __uint_as_float((u).z << 16) * (wgt);                 \
    a5 += __uint_as_float((u).z & 0xffff0000u) * (wgt);         \
    a6 += __uint_as_float((u).w << 16) * (wgt);                 \
    a7 += __uint_as_float((u).w & 0xffff0000u) * (wgt);         \
  }

template <bool OUT_BF16>
__global__ __launch_bounds__(512) void gather_bkt(
    const uint4* __restrict__ feat, const int2* __restrict__ rg,
    const int2* __restrict__ payl, void* __restrict__ outp, int n_dst) {
  __shared__ int2 lp[CAP];
  __shared__ int cnt[BK], base[BK], cnt2[BK];
  const int b = blockIdx.x;
  const int tid = threadIdx.x;
  const int2 r = rg[b];
  const int n = r.y - r.x;
  const int nin = min(n, CAP);
  if (tid < BK) { cnt[tid] = 0; cnt2[tid] = 0; }
  __syncthreads();
  for (int j = tid; j < nin; j += 512)
    atomicAdd(&cnt[payl[r.x + j].y & (BK - 1)], 1);
  __syncthreads();
  if (tid < 64) {                         // exclusive scan of cnt[64], wave 0
    int v = cnt[tid];
    int s = v;
    for (int off = 1; off < 64; off <<= 1) {
      int u = __shfl_up(s, off);
      if (tid >= off) s += u;
    }
    base[tid] = s - v;
  }
  __syncthreads();
  for (int j = tid; j < nin; j += 512) {  // place
    int2 p = payl[r.x + j];
    int dl = p.y & (BK - 1);
    int pos = base[dl] + atomicAdd(&cnt2[dl], 1);
    lp[pos] = p;
  }
  __syncthreads();
  const int wave = tid >> 6;              // 0..7
  const int lane = tid & 63;
  const int rr = lane >> 4;
  const int c  = lane & 15;
  for (int dl = wave; dl < BK; dl += 16) {            // pair (dl, dl+8)
    const int rowA = b * BK + dl;
    const int rowB = b * BK + dl + 8;
    if (rowA >= n_dst) break;
    const bool hasB = (rowB < n_dst);
    const int bgA = base[dl];
    const int lA = cnt[dl];
    const int bgB = hasB ? base[dl + 8] : 0;
    const int lB = hasB ? cnt[dl + 8] : 0;
    const int lmax = max(lA, lB);
    float a0 = 0.f, a1 = 0.f, a2 = 0.f, a3 = 0.f;
    float a4 = 0.f, a5 = 0.f, a6 = 0.f, a7 = 0.f;
    float b0 = 0.f, b1 = 0.f, b2 = 0.f, b3 = 0.f;
    float b4 = 0.f, b5 = 0.f, b6 = 0.f, b7 = 0.f;
    for (int k = rr; k < lmax; k += 4) {  // two independent streams, stride 4
      int2 pA = (k < lA) ? lp[bgA + k] : make_int2(0, 0);
      int2 pB = (k < lB) ? lp[bgB + k] : make_int2(0, 0);
      uint4 uA = feat[(size_t)pA.x * 16 + c];
      uint4 uB = feat[(size_t)pB.x * 16 + c];
      float wA = __uint_as_float((unsigned)pA.y & 0xffff0000u);
      float wB = __uint_as_float((unsigned)pB.y & 0xffff0000u);
      ACC8(a0, a1, a2, a3, a4, a5, a6, a7, wA, uA);
      ACC8(b0, b1, b2, b3, b4, b5, b6, b7, wB, uB);
    }
    if (n > CAP) {                        // overflow tail (never for this input)
      for (int j = CAP + rr; j < n; j += 4) {
        int2 p = payl[r.x + j];
        int pdl = p.y & (BK - 1);
        float wA = (pdl == dl)
            ? __uint_as_float((unsigned)p.y & 0xffff0000u) : 0.f;
        float wB = (hasB && pdl == dl + 8)
            ? __uint_as_float((unsigned)p.y & 0xffff0000u) : 0.f;
        uint4 u = feat[(size_t)p.x * 16 + c];
        ACC8(a0, a1, a2, a3, a4, a5, a6, a7, wA, u);
        ACC8(b0, b1, b2, b3, b4, b5, b6, b7, wB, u);
      }
    }
    a0 += __shfl_xor(a0, 16); a0 += __shfl_xor(a0, 32);
    a1 += __shfl_xor(a1, 16); a1 += __shfl_xor(a1, 32);
    a2 += __shfl_xor(a2, 16); a2 += __shfl_xor(a2, 32);
    a3 += __shfl_xor(a3, 16); a3 += __shfl_xor(a3, 32);
    a4 += __shfl_xor(a4, 16); a4 += __shfl_xor(a4, 32);
    a5 += __shfl_xor(a5, 16); a5 += __shfl_xor(a5, 32);
    a6 += __shfl_xor(a6, 16); a6 += __shfl_xor(a6, 32);
    a7 += __shfl_xor(a7, 16); a7 += __shfl_xor(a7, 32);
    b0 += __shfl_xor(b0, 16); b0 += __shfl_xor(b0, 32);
    b1 += __shfl_xor(b1, 16); b1 += __shfl_xor(b1, 32);
    b2 += __shfl_xor(b2, 16); b2 += __shfl_xor(b2, 32);
    b3 += __shfl_xor(b3, 16); b3 += __shfl_xor(b3, 32);
    b4 += __shfl_xor(b4, 16); b4 += __shfl_xor(b4, 32);
    b5 += __shfl_xor(b5, 16); b5 += __shfl_xor(b5, 32);
    b6 += __shfl_xor(b6, 16); b6 += __shfl_xor(b6, 32);
    b7 += __shfl_xor(b7, 16); b7 += __shfl_xor(b7, 32);
    if (OUT_BF16) {
      if (rr == 0) {
        ((uint4*)outp)[(size_t)rowA * 16 + c] =
            make_uint4(pack_bf16(a0, a1), pack_bf16(a2, a3),
                       pack_bf16(a4, a5), pack_bf16(a6, a7));
        if (hasB)
          ((uint4*)outp)[(size_t)rowB * 16 + c] =
              make_uint4(pack_bf16(b0, b1), pack_bf16(b2, b3),
                         pack_bf16(b4, b5), pack_bf16(b6, b7));
      }
    } else {
      if (rr < 2) {
        ((float4*)outp)[(size_t)rowA * 32 + c * 2 + rr] =
            (rr == 0) ? make_float4(a0, a1, a2, a3)
                      : make_float4(a4, a5, a6, a7);
        if (hasB)
          ((float4*)outp)[(size_t)rowB * 32 + c * 2 + rr] =
              (rr == 0) ? make_float4(b0, b1, b2, b3)
                        : make_float4(b4, b5, b6, b7);
      }
    }
  }
}

// ------------------------------------------------- fallback (round-1 path)
#define COLG 32
__global__ __launch_bounds__(256) void prop_atomic(
    const float* __restrict__ x, const int* __restrict__ src,
    const int* __restrict__ dst, const float* __restrict__ ew,
    float* __restrict__ out, int E) {
  long long idx = (long long)blockIdx.x * blockDim.x + threadIdx.x;
  long long total = (long long)E * COLG;
  if (idx >= total) return;
  int e = (int)(idx >> 5);
  int cg = (int)(idx & 31);
  int s = src[e];
  int d = dst[e];
  float w = ew[e];
  const float4 v = *reinterpret_cast<const float4*>(x + (size_t)s * DIMS + cg * 4);
  float* o = out + (size_t)d * DIMS + cg * 4;
  atomicAdd(o + 0, v.x * w);
  atomicAdd(o + 1, v.y * w);
  atomicAdd(o + 2, v.z * w);
  atomicAdd(o + 3, v.w * w);
}

// --------------------------------------------------------------- launcher

static inline size_t align_up(size_t v, size_t a) { return (v + a - 1) / a * a; }

extern "C" void kernel_launch(void* const* d_in, const int* in_sizes, int n_in,
                              void* d_out, int out_size, void* d_ws, size_t ws_size,
                              hipStream_t stream) {
  const float* x    = (const float*)d_in[0];
  const int*   src0 = (const int*)d_in[1];
  const int*   dst0 = (const int*)d_in[2];
  const float* ew0  = (const float*)d_in[3];
  const int*   src1 = (const int*)d_in[4];
  const int*   dst1 = (const int*)d_in[5];
  const float* ew1  = (const float*)d_in[6];

  const int N_SRC0 = in_sizes[0] / DIMS;  // 100000
  const int E0 = in_sizes[1];             // 1600000
  const int E1 = in_sizes[4];             // 800000
  const int N_DST0 = 50000;
  const int N_DST1 = 25000;

  const int NB0 = (N_DST0 + BK - 1) / BK;   // 782
  const int NB1 = (N_DST1 + BK - 1) / BK;   // 391
  const int NW0 = (E0 + CH - 1) / CH;       // 196
  const int NW1 = (E1 + CH - 1) / CH;       // 98

  float* out = (float*)d_out;

  // --- workspace layout ---
  char* ws = (char*)d_ws;
  size_t off = 0;
  uint4* xb    = (uint4*)(ws + off); off = align_up(off + (size_t)N_SRC0 * 64 * 4, 16);
  uint4* hb    = (uint4*)(ws + off); off = align_up(off + (size_t)N_DST0 * 64 * 4, 16);
  int* wgcnt0  = (int*)(ws + off);   off = align_up(off + (size_t)NW0 * NB0 * 4, 16);
  int* wgcnt1  = (int*)(ws + off);   off = align_up(off + (size_t)NW1 * NB1 * 4, 16);
  int* gcur    = (int*)(ws + off);   off = align_up(off + 2 * 4, 16);
  int2* rg0    = (int2*)(ws + off);  off = align_up(off + (size_t)NB0 * 8, 16);
  int2* rg1    = (int2*)(ws + off);  off = align_up(off + (size_t)NB1 * 8, 16);
  int2* payl0  = (int2*)(ws + off);  off = align_up(off + (size_t)E0 * 8, 16);
  int2* payl1  = (int2*)(ws + off);  off = align_up(off + (size_t)E1 * 8, 16);
  const size_t needed = off;

  if (ws_size < needed) {
    float* h = (float*)d_ws;
    hipMemsetAsync(h, 0, (size_t)N_DST0 * DIMS * 4, stream);
    hipMemsetAsync(out, 0, (size_t)N_DST1 * DIMS * 4, stream);
    long long t0 = (long long)E0 * COLG;
    prop_atomic<<<(int)((t0 + 255) / 256), 256, 0, stream>>>(x, src0, dst0, ew0, h, E0);
    long long t1 = (long long)E1 * COLG;
    prop_atomic<<<(int)((t1 + 255) / 256), 256, 0, stream>>>(h, src1, dst1, ew1, out, E1);
    return;
  }

  const long long n8 = (long long)N_SRC0 * 16;   // uint4 words in xb
  const int cvtBlocks = (int)((n8 + 255) / 256);

  // 0. zero the two payload cursors
  hipMemsetAsync(gcur, 0, 2 * 4, stream);

  // K1: bucket histograms (XCD-swizzled chunks) + f32->bf16 conversion
  hist_cvt<<<NW0 + NW1 + cvtBlocks, 256, 0, stream>>>(
      dst0, dst1, x, xb, wgcnt0, wgcnt1, E0, E1, NB0, NB1, NW0, NW1, n8);

  // K2: per-bucket chunk-prefix scan + atomic base assignment (both stages)
  scan_cols<<<NB0 + NB1, 256, 0, stream>>>(wgcnt0, wgcnt1, gcur, rg0, rg1,
                                           NB0, NB1, NW0, NW1);

  // K3: partition edges into bucket regions (XCD-swizzled chunks)
  partition_k<<<NW0 + NW1, 512, 0, stream>>>(
      src0, dst0, ew0, src1, dst1, ew1, wgcnt0, wgcnt1, rg0, rg1,
      payl0, payl1, E0, E1, NB0, NB1, NW0, NW1);

  // K4: stage-1 gather: hb[dst0] += xb[src0] * ew0  (bf16 out)
  gather_bkt<true><<<NB0, 512, 0, stream>>>(xb, rg0, payl0, (void*)hb, N_DST0);

  // K5: stage-2 gather: out[dst1] += hb[src1] * ew1  (f32 out)
  gather_bkt<false><<<NB1, 512, 0, stream>>>(hb, rg1, payl1, (void*)out, N_DST1);
}